// Round 10
// baseline (235.420 us; speedup 1.0000x reference)
//
#include <hip/hip_runtime.h>

// ---------------------------------------------------------------------------
// MHA: B=2, S=2048, HIDDEN=1024, HEADS=16, HEAD=64, causal.
//   0. cvt_w   : fp32->bf16 for Wq..Wo only (24 MB traffic, ~5 us)
//   1. gemm_qkv: fused QKV projections, 128x128 tile, BK=32, reads fp32
//                q/k/v DIRECTLY (fp32 LDS A-tile + in-register RNE cvt,
//                Q scale folded) — kills cvt_all's 72 MB q/k/v pass.
//                dbuf 48KB -> 3 blk/CU, single barrier/step.
//   2. attn3   : flash attention, const-max exp2 softmax, DBUF K/V,
//                Pl stride 64 -> LDS 40960 = 4 blk/CU  [R9, best]
//   3. gemm_out: out = Xb@Wo^T + bo (fp32), 64x128 tile, RING-3, vmcnt(6)
// A-side fp32 swizzle: row = 32 fp32 = 8 granules of 16B. LDS position p
// holds global granule g = p ^ (row&7). gll16 (8 rows/call, base%8==0):
// lane l -> row l>>3, pos l&7 => source granule (l&7)^((l>>3)&7). Read:
// frag k-cols quad*8..+7 = granules {2q, 2q+1} at positions p0=2q^(R&7),
// p1=p0^1. 16-lane phase: 8 positions x 4 banks = 32 banks, 2 lanes each
// (free). RNE cvt identical to old cvt_all => bit-identical outputs.
// B-side (bf16) swizzle unchanged: g' = g ^ (((row&15)>>1)&3).
// Session ledger (all measured on MI355X):
//  - R3: single barrier/step: total flat; barrier rounds minor.
//  - R5: BK=32 4blk/CU: gemm 59.5->52.9 -> occupancy/TLP is the lever.
//  - R7: qkv ring-3 51.0; attn ring-3 REGRESSED (TLP > depth).
//  - R8: 64x256: FETCH 101->55MB but dur FLAT -> NOT traffic-bound;
//    staging plateau ~13-15 B/cy/CU (m97-family structural ceiling).
//  - R9: attn Pl-64 4blk/CU: total 221.5 (best). gemm_qkv=50.5 is only 23%
//    of total; ~171 us in attn3/gemm_out/cvt_all (<50.4 each) + overhead.
//  - This round: fold q/k/v cvt into gemm_qkv A-path (cvt_all 96->24 MB);
//    gemm_qkv reads fp32 (+2x A bytes, traffic proven non-binding).
// ---------------------------------------------------------------------------

typedef __attribute__((ext_vector_type(8))) short short8;   // 8 bf16
typedef __attribute__((ext_vector_type(4))) float f32x4;
typedef unsigned int u32;
typedef unsigned short u16;

__device__ inline f32x4 mfma16(short8 a, short8 b, f32x4 c) {
    return __builtin_amdgcn_mfma_f32_16x16x32_bf16(a, b, c, 0, 0, 0);
}
__device__ inline u16 f2bf(float f) {
    union { float f; u32 u; } v; v.f = f;
    u32 r = v.u + 0x7fff + ((v.u >> 16) & 1);   // RNE
    return (u16)(r >> 16);
}
// pack two fp32 -> two bf16 with RNE in 5 VALU ops: mem order lo,hi
__device__ inline u32 pk2bf(float lo, float hi) {
    u32 ul = __float_as_uint(lo); ul += 0x7fff + ((ul >> 16) & 1);
    u32 uh = __float_as_uint(hi); uh += 0x7fff + ((uh >> 16) & 1);
    return __builtin_amdgcn_perm(uh, ul, 0x07060302u);
}
__device__ inline void gll16(void* lds, const void* g) {
    __builtin_amdgcn_global_load_lds((const __attribute__((address_space(1))) u32*)g,
                                     (__attribute__((address_space(3))) u32*)lds,
                                     16, 0, 0);
}
// pack two fp32 -> two bf16 (truncation) in one v_perm: mem order lo,hi
__device__ inline u32 pkbf(float hi, float lo) {
    return __builtin_amdgcn_perm(__float_as_uint(hi), __float_as_uint(lo),
                                 0x07060302u);
}

// ---------------------------------------------------------------------------
// W-only conversion: 4 x 1M fp32 -> bf16. 2048 blocks.
// ---------------------------------------------------------------------------
__global__ __launch_bounds__(256)
void cvt_w(const float* __restrict__ wq, const float* __restrict__ wk,
           const float* __restrict__ wv, const float* __restrict__ wo,
           u16* __restrict__ w16) {
    const size_t WSZ = 1u << 20;
    size_t base = ((size_t)blockIdx.x * 256 + threadIdx.x) * 8;
    int wi = (int)(base >> 20); size_t off = base & (WSZ - 1);
    const float* src = wi == 0 ? wq : wi == 1 ? wk : wi == 2 ? wv : wo;
    float4 f0 = *(const float4*)(src + off);
    float4 f1 = *(const float4*)(src + off + 4);
    short8 s = { (short)f2bf(f0.x), (short)f2bf(f0.y),
                 (short)f2bf(f0.z), (short)f2bf(f0.w),
                 (short)f2bf(f1.x), (short)f2bf(f1.y),
                 (short)f2bf(f1.z), (short)f2bf(f1.w) };
    *(short8*)(w16 + (size_t)wi * WSZ + off) = s;
}

// ---------------------------------------------------------------------------
// Fused QKV GEMM, fp32 A inputs. C[m,n] = sum_k A[m,k]*W[n,k].
// grid (8,32,3), 256 thr. 128x128 tile, BK=32, dbuf 48KB (3 blk/CU),
// single barrier per K-step, post-barrier staging (6 gll16/wave/step).
// A staged as fp32, converted to bf16 (RNE) after ds_read; z==0 applies
// the 0.125*log2e exp2-domain Q scale (numerics identical to old cvt_all).
// ---------------------------------------------------------------------------
__global__ __launch_bounds__(256)
void gemm_qkv(const float* __restrict__ qf, const float* __restrict__ kf,
              const float* __restrict__ vf, const u16* __restrict__ w16,
              u16* __restrict__ Qg, u16* __restrict__ Kg, u16* __restrict__ Vt) {
    const int K = 1024;
    __shared__ float Af[2][128 * 32];  // 16 KB per buffer
    __shared__ u16  Bs[2][128 * 32];   // 8 KB per buffer -> total 48 KB
    const int z = blockIdx.z;
    const float* A = z == 0 ? qf : z == 1 ? kf : vf;
    const u16* W = w16 + (size_t)z * (1u << 20);
    const float zscale = (z == 0) ? 0.125f * 1.44269504f : 1.0f;

    const int tid = threadIdx.x, lane = tid & 63, w = tid >> 6;
    const int ln15 = lane & 15, quad = lane >> 4;
    // B side (bf16, 4 granules of 8 u16 per 32-col row) — proven layout
    const int frB  = (ln15 >> 1) & 3;
    const int lrowB = lane >> 2;                  // 16 rows per gll16
    const int lcsB = (((lane & 3) ^ ((lane >> 3) & 3)) << 3);
    // A side (fp32, 8 granules of 4 floats per 32-col row)
    const int lrowA = lane >> 3;                  // 8 rows per gll16
    const int lcsA = (((lane & 7) ^ ((lane >> 3) & 7)) << 2);  // float offset
    const int m0 = blockIdx.y * 128, n0 = blockIdx.x * 128;
    const int wm = (w >> 1) * 64, wn = (w & 1) * 64;

    f32x4 acc[4][4] = {};

    // prologue: stage K-tile 0 into buf 0
    #pragma unroll
    for (int c = 0; c < 4; ++c)
        gll16(&Af[0][(w * 32 + c * 8) * 32],
              &A[(size_t)(m0 + w * 32 + c * 8 + lrowA) * K + lcsA]);
    #pragma unroll
    for (int c = 0; c < 2; ++c)
        gll16(&Bs[0][(w * 32 + c * 16) * 32],
              &W[(size_t)(n0 + w * 32 + c * 16 + lrowB) * K + lcsB]);

    for (int t = 0; t < 32; ++t) {
        const int cur = t & 1, nb = cur ^ 1;
        __asm__ volatile("s_waitcnt vmcnt(0)" ::: "memory");  // own stage landed
        __builtin_amdgcn_s_barrier();                          // all waves landed
        __builtin_amdgcn_sched_barrier(0);

        if (t < 31) {                       // stage tile t+1 (post-barrier: safe)
            const int k0 = (t + 1) * 32;
            #pragma unroll
            for (int c = 0; c < 4; ++c)
                gll16(&Af[nb][(w * 32 + c * 8) * 32],
                      &A[(size_t)(m0 + w * 32 + c * 8 + lrowA) * K + k0 + lcsA]);
            #pragma unroll
            for (int c = 0; c < 2; ++c)
                gll16(&Bs[nb][(w * 32 + c * 16) * 32],
                      &W[(size_t)(n0 + w * 32 + c * 16 + lrowB) * K + k0 + lcsB]);
        }
        __builtin_amdgcn_sched_barrier(0);  // pin stage issue before compute

        short8 a[4], b[4];
        #pragma unroll
        for (int mt = 0; mt < 4; ++mt) {
            const int R = wm + mt * 16 + ln15;
            const int p0 = (2 * quad) ^ (R & 7);   // position of granule 2q
            const int p1 = p0 ^ 1;                 // position of granule 2q+1
            f32x4 fa = *(const f32x4*)&Af[cur][R * 32 + (p0 << 2)];
            f32x4 fb = *(const f32x4*)&Af[cur][R * 32 + (p1 << 2)];
            union { u32 u[4]; short8 s; } au;
            au.u[0] = pk2bf(fa[0] * zscale, fa[1] * zscale);
            au.u[1] = pk2bf(fa[2] * zscale, fa[3] * zscale);
            au.u[2] = pk2bf(fb[0] * zscale, fb[1] * zscale);
            au.u[3] = pk2bf(fb[2] * zscale, fb[3] * zscale);
            a[mt] = au.s;
        }
        #pragma unroll
        for (int nt = 0; nt < 4; ++nt)
            b[nt] = *(const short8*)&Bs[cur][(wn + nt * 16 + ln15) * 32 +
                                            ((quad ^ frB) << 3)];
        #pragma unroll
        for (int mt = 0; mt < 4; ++mt)
            #pragma unroll
            for (int nt = 0; nt < 4; ++nt)
                acc[mt][nt] = mfma16(a[mt], b[nt], acc[mt][nt]);
        // no end-of-step barrier: next iteration's barrier provides it
    }

    #pragma unroll
    for (int mt = 0; mt < 4; ++mt)
        #pragma unroll
        for (int nt = 0; nt < 4; ++nt)
            #pragma unroll
            for (int r = 0; r < 4; ++r) {
                int m = m0 + wm + mt * 16 + quad * 4 + r;
                int n = n0 + wn + nt * 16 + ln15;
                u16 hv = f2bf(acc[mt][nt][r]);
                if (z == 2) {
                    int b_ = m >> 11, s_ = m & 2047, h_ = n >> 6, d_ = n & 63;
                    int kl = s_ & 63;
                    int sp = (s_ & ~63) + (kl & 15) * 4 + (kl >> 4);  // key perm
                    Vt[((size_t)(b_ * 16 + h_) * 64 + d_) * 2048 + sp] = hv;
                } else {
                    u16* dst = z ? Kg : Qg;
                    dst[(size_t)m * 1024 + n] = hv;
                }
            }
}

// ---------------------------------------------------------------------------
// Output GEMM: 64(M)x128(N) tile, BK=64, 512 blocks -> 2 blocks/CU.
// Ring-3 (72KB LDS; grid-limited at 2 blk/CU so LDS growth is free),
// distance-2 prefetch, vmcnt(6) in loop (6 loads per stage per wave).
// ---------------------------------------------------------------------------
__global__ __launch_bounds__(256)
void gemm_out(const u16* __restrict__ A, const u16* __restrict__ W,
              const float* __restrict__ bias, float* __restrict__ out) {
    const int K = 1024;
    __shared__ u16 As[3][64 * 64];     // 8 KB per buffer
    __shared__ u16 Bs[3][128 * 64];    // 16 KB per buffer
    const int id = blockIdx.x;
    const int by = id >> 3, bx = id & 7;   // 8 sharers of A-panel spread XCDs

    const int tid = threadIdx.x, lane = tid & 63, w = tid >> 6;
    const int ln15 = lane & 15, quad = lane >> 4, s7 = ln15 & 7;
    const int lr = lane >> 3;
    const int lcs = (((lane & 7) ^ lr) << 3);
    const int m0 = by * 64, n0 = bx * 128;
    const int wm = (w & 1) * 32, wn = (w >> 1) * 64;

    f32x4 acc[2][4] = {};

    #pragma unroll
    for (int t = 0; t < 2; ++t) {
        #pragma unroll
        for (int c = 0; c < 2; ++c)
            gll16(&As[t][(w * 16 + c * 8) * 64],
                  &A[(size_t)(m0 + w * 16 + c * 8 + lr) * K + t * 64 + lcs]);
        #pragma unroll
        for (int c = 0; c < 4; ++c)
            gll16(&Bs[t][(w * 32 + c * 8) * 64],
                  &W[(size_t)(n0 + w * 32 + c * 8 + lr) * K + t * 64 + lcs]);
    }

    int cur = 0;
    for (int i = 0; i < 16; ++i) {
        if (i < 15) {
            __asm__ volatile("s_waitcnt vmcnt(6)" ::: "memory");
        } else {
            __asm__ volatile("s_waitcnt vmcnt(0)" ::: "memory");
        }
        __builtin_amdgcn_s_barrier();
        __builtin_amdgcn_sched_barrier(0);

        if (i < 14) {
            const int k0 = (i + 2) * 64;
            const int nb = (cur + 2 >= 3) ? cur - 1 : cur + 2;
            #pragma unroll
            for (int c = 0; c < 2; ++c)
                gll16(&As[nb][(w * 16 + c * 8) * 64],
                      &A[(size_t)(m0 + w * 16 + c * 8 + lr) * K + k0 + lcs]);
            #pragma unroll
            for (int c = 0; c < 4; ++c)
                gll16(&Bs[nb][(w * 32 + c * 8) * 64],
                      &W[(size_t)(n0 + w * 32 + c * 8 + lr) * K + k0 + lcs]);
        }
        __builtin_amdgcn_sched_barrier(0);

        #pragma unroll
        for (int kh = 0; kh < 2; ++kh) {
            short8 a[2], b[4];
            #pragma unroll
            for (int mt = 0; mt < 2; ++mt)
                a[mt] = *(const short8*)&As[cur][(wm + mt * 16 + ln15) * 64 +
                                                (((kh * 4 + quad) ^ s7) << 3)];
            #pragma unroll
            for (int nt = 0; nt < 4; ++nt)
                b[nt] = *(const short8*)&Bs[cur][(wn + nt * 16 + ln15) * 64 +
                                                (((kh * 4 + quad) ^ s7) << 3)];
            #pragma unroll
            for (int mt = 0; mt < 2; ++mt)
                #pragma unroll
                for (int nt = 0; nt < 4; ++nt)
                    acc[mt][nt] = mfma16(a[mt], b[nt], acc[mt][nt]);
        }
        cur = (cur == 2) ? 0 : cur + 1;
    }

    #pragma unroll
    for (int mt = 0; mt < 2; ++mt)
        #pragma unroll
        for (int nt = 0; nt < 4; ++nt)
            #pragma unroll
            for (int r = 0; r < 4; ++r) {
                int m = m0 + wm + mt * 16 + quad * 4 + r;
                int n = n0 + wn + nt * 16 + ln15;
                out[(size_t)m * 1024 + n] = acc[mt][nt][r] + bias[n];
            }
}

// ---------------------------------------------------------------------------
// Flash attention, causal. Constant-max softmax in exp2 domain (Q carries
// 0.125*log2e; M0L = 6*log2e). P packed to bf16 by v_perm truncation.
// Unpaired q-tiles: 1024 blocks, qt = 31 - id/32 (heavy first), bh = id&31.
// DBUF K/V, single barrier per kt, post-barrier staging. Pl stride 64 ->
// LDS 40960 -> 4 blocks/CU. [R9 best configuration]
// V is key-permuted (kl -> (kl&15)*4 + (kl>>4)) to match P's packed layout.
// ---------------------------------------------------------------------------
__global__ __launch_bounds__(256)
void attn3(const u16* __restrict__ Qg, const u16* __restrict__ Kg,
           const u16* __restrict__ Vt, u16* __restrict__ Xb) {
    __shared__ u16 Kl[2][64 * 64];     // [key][d], swizzled, 8 KB each
    __shared__ u16 Vl[2][64 * 64];     // [d][key'], swizzled, 8 KB each
    __shared__ u16 Pl[4][16 * 64];     // per-wave P [q][key'], stride 64

    const int id = blockIdx.x;
    const int bh = id & 31, qt = 31 - (id >> 5);   // heavy q-tiles first
    const int b = bh >> 4, h = bh & 15;
    const int tid = threadIdx.x, lane = tid & 63, w = tid >> 6;
    const int ln15 = lane & 15, quad = lane >> 4, s7 = ln15 & 7;
    const int lr = lane >> 3;
    const int lcs = (((lane & 7) ^ lr) << 3);
    const u16* Kbase = Kg + (size_t)b * 2048 * 1024 + h * 64;
    const u16* Vbase = Vt + (size_t)bh * 64 * 2048;
    const float M0L = 8.65617025f;     // 6 * log2(e)
    const int q0 = qt * 64;

    const u16* qrow = Qg + (size_t)(b * 2048 + q0 + w * 16 + ln15) * 1024 + h * 64;
    short8 aq0 = *(const short8*)(qrow + quad * 8);
    short8 aq1 = *(const short8*)(qrow + 32 + quad * 8);
    __asm__ volatile("s_waitcnt vmcnt(0)" ::: "memory");   // drain Q loads

    f32x4 o[4] = {};
    float lsum[4] = {0.f, 0.f, 0.f, 0.f};

    #pragma unroll
    for (int c = 0; c < 2; ++c) {
        const int r0 = w * 16 + c * 8;
        gll16(&Kl[0][r0 * 64], Kbase + (size_t)(r0 + lr) * 1024 + lcs);
        gll16(&Vl[0][r0 * 64], Vbase + (size_t)(r0 + lr) * 2048 + lcs);
    }

    for (int kt = 0; kt <= qt; ++kt) {
        const int cur = kt & 1, nb = cur ^ 1;
        __asm__ volatile("s_waitcnt vmcnt(0)" ::: "memory");  // stage(kt) landed
        __builtin_amdgcn_s_barrier();                          // all waves landed
        __builtin_amdgcn_sched_barrier(0);

        if (kt < qt) {                     // stage kt+1 (post-barrier: safe)
            const int nk = (kt + 1) * 64;
            #pragma unroll
            for (int c = 0; c < 2; ++c) {
                const int r0 = w * 16 + c * 8;
                gll16(&Kl[nb][r0 * 64], Kbase + (size_t)(nk + r0 + lr) * 1024 + lcs);
                gll16(&Vl[nb][r0 * 64], Vbase + (size_t)(r0 + lr) * 2048 + nk + lcs);
            }
        }
        __builtin_amdgcn_sched_barrier(0);

        // S = Q(16x64) . K^T(64x64)
        f32x4 sc[4];
        #pragma unroll
        for (int ct = 0; ct < 4; ++ct) {
            short8 b0 = *(const short8*)&Kl[cur][(ct * 16 + ln15) * 64 +
                                                ((quad ^ s7) << 3)];
            short8 b1 = *(const short8*)&Kl[cur][(ct * 16 + ln15) * 64 +
                                                (((4 + quad) ^ s7) << 3)];
            f32x4 c = {};
            c = mfma16(aq0, b0, c);
            c = mfma16(aq1, b1, c);
            sc[ct] = c;
        }

        const bool diag = (kt == qt);
        #pragma unroll
        for (int r = 0; r < 4; ++r) {
            float s0 = sc[0][r], s1 = sc[1][r], s2 = sc[2][r], s3 = sc[3][r];
            if (diag) {
                const int qq = w * 16 + quad * 4 + r;
                s0 = (ln15      <= qq) ? s0 : -1e30f;
                s1 = (16 + ln15 <= qq) ? s1 : -1e30f;
                s2 = (32 + ln15 <= qq) ? s2 : -1e30f;
                s3 = (48 + ln15 <= qq) ? s3 : -1e30f;
            }
            float p0 = __builtin_amdgcn_exp2f(s0 - M0L);
            float p1 = __builtin_amdgcn_exp2f(s1 - M0L);
            float p2 = __builtin_amdgcn_exp2f(s2 - M0L);
            float p3 = __builtin_amdgcn_exp2f(s3 - M0L);
            uint2 pw = make_uint2(pkbf(p1, p0), pkbf(p3, p2));
            *(uint2*)&Pl[w][(quad * 4 + r) * 64 + ln15 * 4] = pw;
            lsum[r] += (p0 + p1) + (p2 + p3);
        }

        __asm__ volatile("s_waitcnt lgkmcnt(0)" ::: "memory");
        short8 ap0 = *(const short8*)&Pl[w][ln15 * 64 + quad * 8];
        short8 ap1 = *(const short8*)&Pl[w][ln15 * 64 + 32 + quad * 8];

        #pragma unroll
        for (int dt = 0; dt < 4; ++dt) {
            short8 bv0 = *(const short8*)&Vl[cur][(dt * 16 + ln15) * 64 +
                                                 ((quad ^ s7) << 3)];
            short8 bv1 = *(const short8*)&Vl[cur][(dt * 16 + ln15) * 64 +
                                                 (((4 + quad) ^ s7) << 3)];
            o[dt] = mfma16(ap0, bv0, o[dt]);
            o[dt] = mfma16(ap1, bv1, o[dt]);
        }
        // no end barrier: next iteration's barrier provides the separation
    }

    #pragma unroll
    for (int r = 0; r < 4; ++r) {
        float l = lsum[r];
        #pragma unroll
        for (int off = 1; off < 16; off <<= 1)
            l += __shfl_xor(l, off);
        lsum[r] = l;
    }
    #pragma unroll
    for (int dt = 0; dt < 4; ++dt)
        #pragma unroll
        for (int r = 0; r < 4; ++r) {
            int q = q0 + w * 16 + quad * 4 + r;
            Xb[(size_t)(b * 2048 + q) * 1024 + h * 64 + dt * 16 + ln15] =
                f2bf(o[dt][r] / lsum[r]);
        }
}

// ---------------------------------------------------------------------------
extern "C" void kernel_launch(void* const* d_in, const int* in_sizes, int n_in,
                              void* d_out, int out_size, void* d_ws, size_t ws_size,
                              hipStream_t stream) {
    const float* query = (const float*)d_in[0];
    const float* key   = (const float*)d_in[1];
    const float* value = (const float*)d_in[2];
    const float* Wq = (const float*)d_in[4];
    const float* Wk = (const float*)d_in[5];
    const float* Wv = (const float*)d_in[6];
    const float* Wo = (const float*)d_in[7];
    const float* bo = (const float*)d_in[8];
    float* out = (float*)d_out;

    u16* ws  = (u16*)d_ws;
    const size_t T = 1ull << 22;          // 4M u16 = 8 MB
    u16* w16 = ws + 3 * T;                // 4 x 1M elems (layout unchanged)
    u16* Qg  = ws + 4 * T;
    u16* Kg  = ws + 5 * T;
    u16* Vt  = (u16*)d_out;               // dead before gemm_out overwrites out
    u16* Xb  = ws;                        // freed by removing q16/k16/v16
    const size_t WSZ = 1ull << 20;

    cvt_w<<<2048, 256, 0, stream>>>(Wq, Wk, Wv, Wo, w16);

    gemm_qkv<<<dim3(8, 32, 3), 256, 0, stream>>>(query, key, value, w16,
                                                 Qg, Kg, Vt);

    attn3<<<1024, 256, 0, stream>>>(Qg, Kg, Vt, Xb);

    gemm_out<<<512, 256, 0, stream>>>(Xb, w16 + 3 * WSZ, bo, out);
}

// Round 11
// 222.347 us; speedup vs baseline: 1.0588x; 1.0588x over previous
//
#include <hip/hip_runtime.h>

// ---------------------------------------------------------------------------
// MHA: B=2, S=2048, HIDDEN=1024, HEADS=16, HEAD=64, causal.
//   0. cvt_all : fp32->bf16  q(x0.125*log2e), k, v, Wq..Wo
//   1. gemm_qkv: fused QKV projections, 128x128 tile, BK=32, RING-3 LDS
//                (48KB, 3 blk/CU), distance-2 prefetch, vmcnt(4)  [R7/R9]
//   2. attn3   : flash attention, const-max exp2 softmax, DBUF K/V,
//                Pl stride 64 (40960 B = 4 blk/CU), BALANCED qt mapping
//   3. gemm_out: out = Xb@Wo^T + bo (fp32), 64x128 tile, RING-3, vmcnt(6)
// attn3 balance: all 1024 blocks co-resident (4/CU). Round-robin CU
// assignment gives a CU ids {i,i+256,i+512,i+768} -> qt groups {k,k+8,
// k+16,k+24}. Old qt=31-k -> per-CU step sums 52..80 (21% tail). New
// bijective map (j=k>>3, m=k&7): qt = {31-m, m, 23-m, 8+m}[j] -> every
// quartet sums 66 steps exactly. Pure relabeling; correctness unaffected.
// Session ledger (all measured on MI355X):
//  - R3: single barrier/step: total flat; barrier rounds minor.
//  - R5: BK=32 4blk/CU: gemm 59.5->52.9 -> occupancy/TLP is the lever.
//  - R7: qkv ring-3 51.0; attn ring-3 REGRESSED (TLP > depth).
//  - R8: 64x256: FETCH halved but dur FLAT -> NOT traffic-bound; staging
//    plateau ~13-15 B/cy/CU (m97-family structural ceiling).
//  - R9: attn Pl-64 4blk/CU: total 221.5 (BEST).
//  - R10: fp32-A fold FAILED 235us: FETCH 101->200MB (fold defeats 8x
//    reuse amortization), 3.1M LDS conflicts, VALU 42%. LESSON: a
//    conversion consumed N times must be materialized once. Reverted.
//  - This round: R9 + attn3 balanced qt map (one variable).
// ---------------------------------------------------------------------------

typedef __attribute__((ext_vector_type(8))) short short8;   // 8 bf16
typedef __attribute__((ext_vector_type(4))) float f32x4;
typedef unsigned int u32;
typedef unsigned short u16;

__device__ inline f32x4 mfma16(short8 a, short8 b, f32x4 c) {
    return __builtin_amdgcn_mfma_f32_16x16x32_bf16(a, b, c, 0, 0, 0);
}
__device__ inline u16 f2bf(float f) {
    union { float f; u32 u; } v; v.f = f;
    u32 r = v.u + 0x7fff + ((v.u >> 16) & 1);   // RNE
    return (u16)(r >> 16);
}
__device__ inline void gll16(void* lds, const void* g) {
    __builtin_amdgcn_global_load_lds((const __attribute__((address_space(1))) u32*)g,
                                     (__attribute__((address_space(3))) u32*)lds,
                                     16, 0, 0);
}
// pack two fp32 -> two bf16 (truncation) in one v_perm: mem order lo,hi
__device__ inline u32 pkbf(float hi, float lo) {
    return __builtin_amdgcn_perm(__float_as_uint(hi), __float_as_uint(lo),
                                 0x07060302u);
}

// ---------------------------------------------------------------------------
__global__ __launch_bounds__(256)
void cvt_all(const float* __restrict__ q, const float* __restrict__ k,
             const float* __restrict__ v, const float* __restrict__ wq,
             const float* __restrict__ wk, const float* __restrict__ wv,
             const float* __restrict__ wo,
             u16* __restrict__ q16, u16* __restrict__ k16,
             u16* __restrict__ v16, u16* __restrict__ w16) {
    const size_t QKV = 1u << 22;
    const size_t WSZ = 1u << 20;
    size_t base = ((size_t)blockIdx.x * 256 + threadIdx.x) * 8;
    const float* src; u16* dst; size_t off; float scale = 1.0f;
    if (base < QKV)            { src = q; dst = q16; off = base;
                                 scale = 0.125f * 1.44269504f; }   // exp2 domain
    else if (base < 2 * QKV)   { src = k; dst = k16; off = base - QKV;     }
    else if (base < 3 * QKV)   { src = v; dst = v16; off = base - 2 * QKV; }
    else {
        size_t wb = base - 3 * QKV;
        int wi = (int)(wb >> 20); off = wb & (WSZ - 1);
        src = wi == 0 ? wq : wi == 1 ? wk : wi == 2 ? wv : wo;
        dst = w16 + (size_t)wi * WSZ;
    }
    float4 f0 = *(const float4*)(src + off);
    float4 f1 = *(const float4*)(src + off + 4);
    short8 s = { (short)f2bf(f0.x * scale), (short)f2bf(f0.y * scale),
                 (short)f2bf(f0.z * scale), (short)f2bf(f0.w * scale),
                 (short)f2bf(f1.x * scale), (short)f2bf(f1.y * scale),
                 (short)f2bf(f1.z * scale), (short)f2bf(f1.w * scale) };
    *(short8*)(dst + off) = s;
}

// ---------------------------------------------------------------------------
// Fused QKV GEMM. C[m,n] = sum_k A[m,k]*W[n,k]. grid (8,32,3), 256 thr.
// 128x128 tile, BK=32, ring-3 LDS (48KB), distance-2 prefetch, vmcnt(4).
// [R7/R9 configuration — best measured: 50.5 us]
// ---------------------------------------------------------------------------
__global__ __launch_bounds__(256)
void gemm_qkv(const u16* __restrict__ q16, const u16* __restrict__ k16,
              const u16* __restrict__ v16, const u16* __restrict__ w16,
              u16* __restrict__ Qg, u16* __restrict__ Kg, u16* __restrict__ Vt) {
    const int K = 1024;
    __shared__ u16 As[3][128 * 32];    // 8 KB per buffer
    __shared__ u16 Bs[3][128 * 32];    // total 48 KB
    const int z = blockIdx.z;
    const u16* A = z == 0 ? q16 : z == 1 ? k16 : v16;
    const u16* W = w16 + (size_t)z * (1u << 20);

    const int tid = threadIdx.x, lane = tid & 63, w = tid >> 6;
    const int ln15 = lane & 15, quad = lane >> 4;
    const int fr = (ln15 >> 1) & 3;              // read-side granule swizzle
    const int lrow = lane >> 2;                  // 16 rows per gll16
    const int lcs = (((lane & 3) ^ ((lane >> 3) & 3)) << 3);  // src granule perm
    const int m0 = blockIdx.y * 128, n0 = blockIdx.x * 128;
    const int wm = (w >> 1) * 64, wn = (w & 1) * 64;

    f32x4 acc[4][4] = {};

    // prologue: stage K-tiles 0 and 1 (4 loads each per wave -> 8 in flight)
    #pragma unroll
    for (int t = 0; t < 2; ++t)
        #pragma unroll
        for (int c = 0; c < 2; ++c) {
            gll16(&As[t][(w * 32 + c * 16) * 32],
                  &A[(size_t)(m0 + w * 32 + c * 16 + lrow) * K + t * 32 + lcs]);
            gll16(&Bs[t][(w * 32 + c * 16) * 32],
                  &W[(size_t)(n0 + w * 32 + c * 16 + lrow) * K + t * 32 + lcs]);
        }

    int cur = 0;                       // t % 3
    for (int t = 0; t < 32; ++t) {
        if (t < 31) {
            __asm__ volatile("s_waitcnt vmcnt(4)" ::: "memory");  // stage(t) landed
        } else {
            __asm__ volatile("s_waitcnt vmcnt(0)" ::: "memory");
        }
        __builtin_amdgcn_s_barrier();                              // all waves landed
        __builtin_amdgcn_sched_barrier(0);

        if (t < 30) {                  // stage tile t+2 (post-barrier: safe)
            const int k0 = (t + 2) * 32;
            const int nb = (cur + 2 >= 3) ? cur - 1 : cur + 2;     // (t+2)%3
            #pragma unroll
            for (int c = 0; c < 2; ++c) {
                gll16(&As[nb][(w * 32 + c * 16) * 32],
                      &A[(size_t)(m0 + w * 32 + c * 16 + lrow) * K + k0 + lcs]);
                gll16(&Bs[nb][(w * 32 + c * 16) * 32],
                      &W[(size_t)(n0 + w * 32 + c * 16 + lrow) * K + k0 + lcs]);
            }
        }
        __builtin_amdgcn_sched_barrier(0);  // pin stage issue before compute

        short8 a[4], b[4];
        #pragma unroll
        for (int mt = 0; mt < 4; ++mt)
            a[mt] = *(const short8*)&As[cur][(wm + mt * 16 + ln15) * 32 +
                                            ((quad ^ fr) << 3)];
        #pragma unroll
        for (int nt = 0; nt < 4; ++nt)
            b[nt] = *(const short8*)&Bs[cur][(wn + nt * 16 + ln15) * 32 +
                                            ((quad ^ fr) << 3)];
        #pragma unroll
        for (int mt = 0; mt < 4; ++mt)
            #pragma unroll
            for (int nt = 0; nt < 4; ++nt)
                acc[mt][nt] = mfma16(a[mt], b[nt], acc[mt][nt]);

        cur = (cur == 2) ? 0 : cur + 1;
        // no end-of-step barrier: next iteration's barrier provides it
    }

    #pragma unroll
    for (int mt = 0; mt < 4; ++mt)
        #pragma unroll
        for (int nt = 0; nt < 4; ++nt)
            #pragma unroll
            for (int r = 0; r < 4; ++r) {
                int m = m0 + wm + mt * 16 + quad * 4 + r;
                int n = n0 + wn + nt * 16 + ln15;
                u16 hv = f2bf(acc[mt][nt][r]);
                if (z == 2) {
                    int b_ = m >> 11, s_ = m & 2047, h_ = n >> 6, d_ = n & 63;
                    int kl = s_ & 63;
                    int sp = (s_ & ~63) + (kl & 15) * 4 + (kl >> 4);  // key perm
                    Vt[((size_t)(b_ * 16 + h_) * 64 + d_) * 2048 + sp] = hv;
                } else {
                    u16* dst = z ? Kg : Qg;
                    dst[(size_t)m * 1024 + n] = hv;
                }
            }
}

// ---------------------------------------------------------------------------
// Output GEMM: 64(M)x128(N) tile, BK=64, 512 blocks -> 2 blocks/CU.
// Ring-3 (72KB LDS; grid-limited at 2 blk/CU so LDS growth is free),
// distance-2 prefetch, vmcnt(6) in loop (6 loads per stage per wave).
// ---------------------------------------------------------------------------
__global__ __launch_bounds__(256)
void gemm_out(const u16* __restrict__ A, const u16* __restrict__ W,
              const float* __restrict__ bias, float* __restrict__ out) {
    const int K = 1024;
    __shared__ u16 As[3][64 * 64];     // 8 KB per buffer
    __shared__ u16 Bs[3][128 * 64];    // 16 KB per buffer
    const int id = blockIdx.x;
    const int by = id >> 3, bx = id & 7;   // 8 sharers of A-panel spread XCDs

    const int tid = threadIdx.x, lane = tid & 63, w = tid >> 6;
    const int ln15 = lane & 15, quad = lane >> 4, s7 = ln15 & 7;
    const int lr = lane >> 3;
    const int lcs = (((lane & 7) ^ lr) << 3);
    const int m0 = by * 64, n0 = bx * 128;
    const int wm = (w & 1) * 32, wn = (w >> 1) * 64;

    f32x4 acc[2][4] = {};

    #pragma unroll
    for (int t = 0; t < 2; ++t) {
        #pragma unroll
        for (int c = 0; c < 2; ++c)
            gll16(&As[t][(w * 16 + c * 8) * 64],
                  &A[(size_t)(m0 + w * 16 + c * 8 + lr) * K + t * 64 + lcs]);
        #pragma unroll
        for (int c = 0; c < 4; ++c)
            gll16(&Bs[t][(w * 32 + c * 8) * 64],
                  &W[(size_t)(n0 + w * 32 + c * 8 + lr) * K + t * 64 + lcs]);
    }

    int cur = 0;
    for (int i = 0; i < 16; ++i) {
        if (i < 15) {
            __asm__ volatile("s_waitcnt vmcnt(6)" ::: "memory");
        } else {
            __asm__ volatile("s_waitcnt vmcnt(0)" ::: "memory");
        }
        __builtin_amdgcn_s_barrier();
        __builtin_amdgcn_sched_barrier(0);

        if (i < 14) {
            const int k0 = (i + 2) * 64;
            const int nb = (cur + 2 >= 3) ? cur - 1 : cur + 2;
            #pragma unroll
            for (int c = 0; c < 2; ++c)
                gll16(&As[nb][(w * 16 + c * 8) * 64],
                      &A[(size_t)(m0 + w * 16 + c * 8 + lr) * K + k0 + lcs]);
            #pragma unroll
            for (int c = 0; c < 4; ++c)
                gll16(&Bs[nb][(w * 32 + c * 8) * 64],
                      &W[(size_t)(n0 + w * 32 + c * 8 + lr) * K + k0 + lcs]);
        }
        __builtin_amdgcn_sched_barrier(0);

        #pragma unroll
        for (int kh = 0; kh < 2; ++kh) {
            short8 a[2], b[4];
            #pragma unroll
            for (int mt = 0; mt < 2; ++mt)
                a[mt] = *(const short8*)&As[cur][(wm + mt * 16 + ln15) * 64 +
                                                (((kh * 4 + quad) ^ s7) << 3)];
            #pragma unroll
            for (int nt = 0; nt < 4; ++nt)
                b[nt] = *(const short8*)&Bs[cur][(wn + nt * 16 + ln15) * 64 +
                                                (((kh * 4 + quad) ^ s7) << 3)];
            #pragma unroll
            for (int mt = 0; mt < 2; ++mt)
                #pragma unroll
                for (int nt = 0; nt < 4; ++nt)
                    acc[mt][nt] = mfma16(a[mt], b[nt], acc[mt][nt]);
        }
        cur = (cur == 2) ? 0 : cur + 1;
    }

    #pragma unroll
    for (int mt = 0; mt < 2; ++mt)
        #pragma unroll
        for (int nt = 0; nt < 4; ++nt)
            #pragma unroll
            for (int r = 0; r < 4; ++r) {
                int m = m0 + wm + mt * 16 + quad * 4 + r;
                int n = n0 + wn + nt * 16 + ln15;
                out[(size_t)m * 1024 + n] = acc[mt][nt][r] + bias[n];
            }
}

// ---------------------------------------------------------------------------
// Flash attention, causal. Constant-max softmax in exp2 domain (Q carries
// 0.125*log2e; M0L = 6*log2e). P packed to bf16 by v_perm truncation.
// 1024 blocks, bh = id&31; BALANCED qt map: k=id>>5, j=k>>3, m=k&7,
// qt = {31-m, m, 23-m, 8+m}[j] — co-resident quartets {k,k+8,k+16,k+24}
// sum to 66 steps exactly (was 52..80). Bijective over [0,32).
// DBUF K/V, single barrier per kt, post-barrier staging. Pl stride 64 ->
// LDS 40960 -> 4 blocks/CU. [R9 + balance]
// V is key-permuted (kl -> (kl&15)*4 + (kl>>4)) to match P's packed layout.
// ---------------------------------------------------------------------------
__global__ __launch_bounds__(256)
void attn3(const u16* __restrict__ Qg, const u16* __restrict__ Kg,
           const u16* __restrict__ Vt, u16* __restrict__ Xb) {
    __shared__ u16 Kl[2][64 * 64];     // [key][d], swizzled, 8 KB each
    __shared__ u16 Vl[2][64 * 64];     // [d][key'], swizzled, 8 KB each
    __shared__ u16 Pl[4][16 * 64];     // per-wave P [q][key'], stride 64

    const int id = blockIdx.x;
    const int bh = id & 31;
    const int kk = id >> 5, jj = kk >> 3, mm = kk & 7;
    const int qt = (jj == 0) ? 31 - mm : (jj == 1) ? mm
                 : (jj == 2) ? 23 - mm : 8 + mm;   // balanced quartets
    const int b = bh >> 4, h = bh & 15;
    const int tid = threadIdx.x, lane = tid & 63, w = tid >> 6;
    const int ln15 = lane & 15, quad = lane >> 4, s7 = ln15 & 7;
    const int lr = lane >> 3;
    const int lcs = (((lane & 7) ^ lr) << 3);
    const u16* Kbase = Kg + (size_t)b * 2048 * 1024 + h * 64;
    const u16* Vbase = Vt + (size_t)bh * 64 * 2048;
    const float M0L = 8.65617025f;     // 6 * log2(e)
    const int q0 = qt * 64;

    const u16* qrow = Qg + (size_t)(b * 2048 + q0 + w * 16 + ln15) * 1024 + h * 64;
    short8 aq0 = *(const short8*)(qrow + quad * 8);
    short8 aq1 = *(const short8*)(qrow + 32 + quad * 8);
    __asm__ volatile("s_waitcnt vmcnt(0)" ::: "memory");   // drain Q loads

    f32x4 o[4] = {};
    float lsum[4] = {0.f, 0.f, 0.f, 0.f};

    #pragma unroll
    for (int c = 0; c < 2; ++c) {
        const int r0 = w * 16 + c * 8;
        gll16(&Kl[0][r0 * 64], Kbase + (size_t)(r0 + lr) * 1024 + lcs);
        gll16(&Vl[0][r0 * 64], Vbase + (size_t)(r0 + lr) * 2048 + lcs);
    }

    for (int kt = 0; kt <= qt; ++kt) {
        const int cur = kt & 1, nb = cur ^ 1;
        __asm__ volatile("s_waitcnt vmcnt(0)" ::: "memory");  // stage(kt) landed
        __builtin_amdgcn_s_barrier();                          // all waves landed
        __builtin_amdgcn_sched_barrier(0);

        if (kt < qt) {                     // stage kt+1 (post-barrier: safe)
            const int nk = (kt + 1) * 64;
            #pragma unroll
            for (int c = 0; c < 2; ++c) {
                const int r0 = w * 16 + c * 8;
                gll16(&Kl[nb][r0 * 64], Kbase + (size_t)(nk + r0 + lr) * 1024 + lcs);
                gll16(&Vl[nb][r0 * 64], Vbase + (size_t)(r0 + lr) * 2048 + nk + lcs);
            }
        }
        __builtin_amdgcn_sched_barrier(0);

        // S = Q(16x64) . K^T(64x64)
        f32x4 sc[4];
        #pragma unroll
        for (int ct = 0; ct < 4; ++ct) {
            short8 b0 = *(const short8*)&Kl[cur][(ct * 16 + ln15) * 64 +
                                                ((quad ^ s7) << 3)];
            short8 b1 = *(const short8*)&Kl[cur][(ct * 16 + ln15) * 64 +
                                                (((4 + quad) ^ s7) << 3)];
            f32x4 c = {};
            c = mfma16(aq0, b0, c);
            c = mfma16(aq1, b1, c);
            sc[ct] = c;
        }

        const bool diag = (kt == qt);
        #pragma unroll
        for (int r = 0; r < 4; ++r) {
            float s0 = sc[0][r], s1 = sc[1][r], s2 = sc[2][r], s3 = sc[3][r];
            if (diag) {
                const int qq = w * 16 + quad * 4 + r;
                s0 = (ln15      <= qq) ? s0 : -1e30f;
                s1 = (16 + ln15 <= qq) ? s1 : -1e30f;
                s2 = (32 + ln15 <= qq) ? s2 : -1e30f;
                s3 = (48 + ln15 <= qq) ? s3 : -1e30f;
            }
            float p0 = __builtin_amdgcn_exp2f(s0 - M0L);
            float p1 = __builtin_amdgcn_exp2f(s1 - M0L);
            float p2 = __builtin_amdgcn_exp2f(s2 - M0L);
            float p3 = __builtin_amdgcn_exp2f(s3 - M0L);
            uint2 pw = make_uint2(pkbf(p1, p0), pkbf(p3, p2));
            *(uint2*)&Pl[w][(quad * 4 + r) * 64 + ln15 * 4] = pw;
            lsum[r] += (p0 + p1) + (p2 + p3);
        }

        __asm__ volatile("s_waitcnt lgkmcnt(0)" ::: "memory");
        short8 ap0 = *(const short8*)&Pl[w][ln15 * 64 + quad * 8];
        short8 ap1 = *(const short8*)&Pl[w][ln15 * 64 + 32 + quad * 8];

        #pragma unroll
        for (int dt = 0; dt < 4; ++dt) {
            short8 bv0 = *(const short8*)&Vl[cur][(dt * 16 + ln15) * 64 +
                                                 ((quad ^ s7) << 3)];
            short8 bv1 = *(const short8*)&Vl[cur][(dt * 16 + ln15) * 64 +
                                                 (((4 + quad) ^ s7) << 3)];
            o[dt] = mfma16(ap0, bv0, o[dt]);
            o[dt] = mfma16(ap1, bv1, o[dt]);
        }
        // no end barrier: next iteration's barrier provides the separation
    }

    #pragma unroll
    for (int r = 0; r < 4; ++r) {
        float l = lsum[r];
        #pragma unroll
        for (int off = 1; off < 16; off <<= 1)
            l += __shfl_xor(l, off);
        lsum[r] = l;
    }
    #pragma unroll
    for (int dt = 0; dt < 4; ++dt)
        #pragma unroll
        for (int r = 0; r < 4; ++r) {
            int q = q0 + w * 16 + quad * 4 + r;
            Xb[(size_t)(b * 2048 + q) * 1024 + h * 64 + dt * 16 + ln15] =
                f2bf(o[dt][r] / lsum[r]);
        }
}

// ---------------------------------------------------------------------------
extern "C" void kernel_launch(void* const* d_in, const int* in_sizes, int n_in,
                              void* d_out, int out_size, void* d_ws, size_t ws_size,
                              hipStream_t stream) {
    const float* query = (const float*)d_in[0];
    const float* key   = (const float*)d_in[1];
    const float* value = (const float*)d_in[2];
    const float* Wq = (const float*)d_in[4];
    const float* Wk = (const float*)d_in[5];
    const float* Wv = (const float*)d_in[6];
    const float* Wo = (const float*)d_in[7];
    const float* bo = (const float*)d_in[8];
    float* out = (float*)d_out;

    u16* ws  = (u16*)d_ws;
    const size_t T = 1ull << 22;          // 4M u16 = 8 MB
    u16* q16 = ws;
    u16* k16 = ws + T;
    u16* v16 = ws + 2 * T;
    u16* w16 = ws + 3 * T;                // 4 x 1M elems
    u16* Qg  = ws + 4 * T;
    u16* Kg  = ws + 5 * T;
    u16* Vt  = (u16*)d_out;               // dead before gemm_out overwrites out
    u16* Xb  = q16;                       // q16 dead after gemm_qkv
    const size_t WSZ = 1ull << 20;

    cvt_all<<<8192, 256, 0, stream>>>(query, key, value, Wq, Wk, Wv, Wo,
                                      q16, k16, v16, w16);

    gemm_qkv<<<dim3(8, 32, 3), 256, 0, stream>>>(q16, k16, v16, w16, Qg, Kg, Vt);

    attn3<<<1024, 256, 0, stream>>>(Qg, Kg, Vt, Xb);

    gemm_out<<<512, 256, 0, stream>>>(Xb, w16 + 3 * WSZ, bo, out);
}

// Round 12
// 219.918 us; speedup vs baseline: 1.0705x; 1.0110x over previous
//
#include <hip/hip_runtime.h>

// ---------------------------------------------------------------------------
// MHA: B=2, S=2048, HIDDEN=1024, HEADS=16, HEAD=64, causal.
//   0. cvt_all : fp32->bf16  q(x0.125*log2e), k, v, Wq..Wo
//   1. gemm_qkv: fused QKV projections, 128x128 tile, BK=32, RING-3 LDS
//                (48KB, 3 blk/CU), distance-2 prefetch, vmcnt(4)  [R7/R9]
//   2. attn3   : flash attention, const-max exp2 softmax, DBUF K/V,
//                Pl stride 64 (40960 B = 4 blk/CU), balanced qt map,
//                s_setprio(1) around MFMA clusters (T5: attn-applicable)
//   3. gemm_out: 64x64 tile, BK=64, 1024 blocks -> 4 blk/CU one round,
//                dbuf 32KB, single barrier/step  [R5 geometry lesson]
// Session ledger (all measured on MI355X):
//  - R3: single barrier/step: +2.5us. R5: BK=32 4blk/CU: +6us (occupancy
//    is THE lever). R7: qkv ring-3 +2; attn ring-3 REGRESSED (TLP>depth).
//  - R8: 64x256: FETCH halved, dur FLAT -> staging plateau ~13-15 B/cy/CU
//    (m97-family structural ceiling), NOT traffic-bound.
//  - R9: attn Pl-64 4blk/CU: total 221.5 (BEST). R10: fp32-A fold FAILED
//    (fold defeats 8x reuse; materialize conversions once). R11: balanced
//    qt map NEUTRAL (kept, harmless).
//  - This round: gemm_out 2->4 blk/CU (64x64 tile, grid 1024, one round;
//    mirrors R5) + attn3 setprio around MFMA (guide T5: +4-7% attn when
//    independent blocks co-reside; GEMM-null case doesn't apply).
// ---------------------------------------------------------------------------

typedef __attribute__((ext_vector_type(8))) short short8;   // 8 bf16
typedef __attribute__((ext_vector_type(4))) float f32x4;
typedef unsigned int u32;
typedef unsigned short u16;

__device__ inline f32x4 mfma16(short8 a, short8 b, f32x4 c) {
    return __builtin_amdgcn_mfma_f32_16x16x32_bf16(a, b, c, 0, 0, 0);
}
__device__ inline u16 f2bf(float f) {
    union { float f; u32 u; } v; v.f = f;
    u32 r = v.u + 0x7fff + ((v.u >> 16) & 1);   // RNE
    return (u16)(r >> 16);
}
__device__ inline void gll16(void* lds, const void* g) {
    __builtin_amdgcn_global_load_lds((const __attribute__((address_space(1))) u32*)g,
                                     (__attribute__((address_space(3))) u32*)lds,
                                     16, 0, 0);
}
// pack two fp32 -> two bf16 (truncation) in one v_perm: mem order lo,hi
__device__ inline u32 pkbf(float hi, float lo) {
    return __builtin_amdgcn_perm(__float_as_uint(hi), __float_as_uint(lo),
                                 0x07060302u);
}

// ---------------------------------------------------------------------------
__global__ __launch_bounds__(256)
void cvt_all(const float* __restrict__ q, const float* __restrict__ k,
             const float* __restrict__ v, const float* __restrict__ wq,
             const float* __restrict__ wk, const float* __restrict__ wv,
             const float* __restrict__ wo,
             u16* __restrict__ q16, u16* __restrict__ k16,
             u16* __restrict__ v16, u16* __restrict__ w16) {
    const size_t QKV = 1u << 22;
    const size_t WSZ = 1u << 20;
    size_t base = ((size_t)blockIdx.x * 256 + threadIdx.x) * 8;
    const float* src; u16* dst; size_t off; float scale = 1.0f;
    if (base < QKV)            { src = q; dst = q16; off = base;
                                 scale = 0.125f * 1.44269504f; }   // exp2 domain
    else if (base < 2 * QKV)   { src = k; dst = k16; off = base - QKV;     }
    else if (base < 3 * QKV)   { src = v; dst = v16; off = base - 2 * QKV; }
    else {
        size_t wb = base - 3 * QKV;
        int wi = (int)(wb >> 20); off = wb & (WSZ - 1);
        src = wi == 0 ? wq : wi == 1 ? wk : wi == 2 ? wv : wo;
        dst = w16 + (size_t)wi * WSZ;
    }
    float4 f0 = *(const float4*)(src + off);
    float4 f1 = *(const float4*)(src + off + 4);
    short8 s = { (short)f2bf(f0.x * scale), (short)f2bf(f0.y * scale),
                 (short)f2bf(f0.z * scale), (short)f2bf(f0.w * scale),
                 (short)f2bf(f1.x * scale), (short)f2bf(f1.y * scale),
                 (short)f2bf(f1.z * scale), (short)f2bf(f1.w * scale) };
    *(short8*)(dst + off) = s;
}

// ---------------------------------------------------------------------------
// Fused QKV GEMM. C[m,n] = sum_k A[m,k]*W[n,k]. grid (8,32,3), 256 thr.
// 128x128 tile, BK=32, ring-3 LDS (48KB), distance-2 prefetch, vmcnt(4).
// [R7/R9 configuration — best measured: 50.5 us]
// ---------------------------------------------------------------------------
__global__ __launch_bounds__(256)
void gemm_qkv(const u16* __restrict__ q16, const u16* __restrict__ k16,
              const u16* __restrict__ v16, const u16* __restrict__ w16,
              u16* __restrict__ Qg, u16* __restrict__ Kg, u16* __restrict__ Vt) {
    const int K = 1024;
    __shared__ u16 As[3][128 * 32];    // 8 KB per buffer
    __shared__ u16 Bs[3][128 * 32];    // total 48 KB
    const int z = blockIdx.z;
    const u16* A = z == 0 ? q16 : z == 1 ? k16 : v16;
    const u16* W = w16 + (size_t)z * (1u << 20);

    const int tid = threadIdx.x, lane = tid & 63, w = tid >> 6;
    const int ln15 = lane & 15, quad = lane >> 4;
    const int fr = (ln15 >> 1) & 3;              // read-side granule swizzle
    const int lrow = lane >> 2;                  // 16 rows per gll16
    const int lcs = (((lane & 3) ^ ((lane >> 3) & 3)) << 3);  // src granule perm
    const int m0 = blockIdx.y * 128, n0 = blockIdx.x * 128;
    const int wm = (w >> 1) * 64, wn = (w & 1) * 64;

    f32x4 acc[4][4] = {};

    // prologue: stage K-tiles 0 and 1 (4 loads each per wave -> 8 in flight)
    #pragma unroll
    for (int t = 0; t < 2; ++t)
        #pragma unroll
        for (int c = 0; c < 2; ++c) {
            gll16(&As[t][(w * 32 + c * 16) * 32],
                  &A[(size_t)(m0 + w * 32 + c * 16 + lrow) * K + t * 32 + lcs]);
            gll16(&Bs[t][(w * 32 + c * 16) * 32],
                  &W[(size_t)(n0 + w * 32 + c * 16 + lrow) * K + t * 32 + lcs]);
        }

    int cur = 0;                       // t % 3
    for (int t = 0; t < 32; ++t) {
        if (t < 31) {
            __asm__ volatile("s_waitcnt vmcnt(4)" ::: "memory");  // stage(t) landed
        } else {
            __asm__ volatile("s_waitcnt vmcnt(0)" ::: "memory");
        }
        __builtin_amdgcn_s_barrier();                              // all waves landed
        __builtin_amdgcn_sched_barrier(0);

        if (t < 30) {                  // stage tile t+2 (post-barrier: safe)
            const int k0 = (t + 2) * 32;
            const int nb = (cur + 2 >= 3) ? cur - 1 : cur + 2;     // (t+2)%3
            #pragma unroll
            for (int c = 0; c < 2; ++c) {
                gll16(&As[nb][(w * 32 + c * 16) * 32],
                      &A[(size_t)(m0 + w * 32 + c * 16 + lrow) * K + k0 + lcs]);
                gll16(&Bs[nb][(w * 32 + c * 16) * 32],
                      &W[(size_t)(n0 + w * 32 + c * 16 + lrow) * K + k0 + lcs]);
            }
        }
        __builtin_amdgcn_sched_barrier(0);  // pin stage issue before compute

        short8 a[4], b[4];
        #pragma unroll
        for (int mt = 0; mt < 4; ++mt)
            a[mt] = *(const short8*)&As[cur][(wm + mt * 16 + ln15) * 32 +
                                            ((quad ^ fr) << 3)];
        #pragma unroll
        for (int nt = 0; nt < 4; ++nt)
            b[nt] = *(const short8*)&Bs[cur][(wn + nt * 16 + ln15) * 32 +
                                            ((quad ^ fr) << 3)];
        #pragma unroll
        for (int mt = 0; mt < 4; ++mt)
            #pragma unroll
            for (int nt = 0; nt < 4; ++nt)
                acc[mt][nt] = mfma16(a[mt], b[nt], acc[mt][nt]);

        cur = (cur == 2) ? 0 : cur + 1;
        // no end-of-step barrier: next iteration's barrier provides it
    }

    #pragma unroll
    for (int mt = 0; mt < 4; ++mt)
        #pragma unroll
        for (int nt = 0; nt < 4; ++nt)
            #pragma unroll
            for (int r = 0; r < 4; ++r) {
                int m = m0 + wm + mt * 16 + quad * 4 + r;
                int n = n0 + wn + nt * 16 + ln15;
                u16 hv = f2bf(acc[mt][nt][r]);
                if (z == 2) {
                    int b_ = m >> 11, s_ = m & 2047, h_ = n >> 6, d_ = n & 63;
                    int kl = s_ & 63;
                    int sp = (s_ & ~63) + (kl & 15) * 4 + (kl >> 4);  // key perm
                    Vt[((size_t)(b_ * 16 + h_) * 64 + d_) * 2048 + sp] = hv;
                } else {
                    u16* dst = z ? Kg : Qg;
                    dst[(size_t)m * 1024 + n] = hv;
                }
            }
}

// ---------------------------------------------------------------------------
// Output GEMM: 64x64 tile, BK=64, 1024 blocks -> 4 blocks/CU, ONE round.
// dbuf 32KB, single barrier/step, post-barrier staging (R5 geometry).
// Waves 2x2: each wave owns a 32x32 output quadrant (acc[2][2]).
// 16 sharers of each A-panel (vs 8 before) — traffic proven non-binding.
// ---------------------------------------------------------------------------
__global__ __launch_bounds__(256)
void gemm_out(const u16* __restrict__ A, const u16* __restrict__ W,
              const float* __restrict__ bias, float* __restrict__ out) {
    const int K = 1024;
    __shared__ u16 As[2][64 * 64];     // 8 KB per buffer
    __shared__ u16 Bs[2][64 * 64];     // 8 KB per buffer -> 32 KB total
    const int id = blockIdx.x;
    const int by = id >> 4, bx = id & 15;  // 16 sharers of A-panel spread XCDs

    const int tid = threadIdx.x, lane = tid & 63, w = tid >> 6;
    const int ln15 = lane & 15, quad = lane >> 4, s7 = ln15 & 7;
    const int lr = lane >> 3;
    const int lcs = (((lane & 7) ^ lr) << 3);
    const int m0 = by * 64, n0 = bx * 64;
    const int wm = (w & 1) * 32, wn = (w >> 1) * 32;

    f32x4 acc[2][2] = {};

    #pragma unroll
    for (int c = 0; c < 2; ++c) {
        gll16(&As[0][(w * 16 + c * 8) * 64],
              &A[(size_t)(m0 + w * 16 + c * 8 + lr) * K + lcs]);
        gll16(&Bs[0][(w * 16 + c * 8) * 64],
              &W[(size_t)(n0 + w * 16 + c * 8 + lr) * K + lcs]);
    }

    for (int i = 0; i < 16; ++i) {
        const int cur = i & 1, nb = cur ^ 1;
        __asm__ volatile("s_waitcnt vmcnt(0)" ::: "memory");  // own stage landed
        __builtin_amdgcn_s_barrier();                          // all waves landed
        __builtin_amdgcn_sched_barrier(0);

        if (i < 15) {                       // stage tile i+1 (post-barrier: safe)
            const int k0 = (i + 1) * 64;
            #pragma unroll
            for (int c = 0; c < 2; ++c) {
                gll16(&As[nb][(w * 16 + c * 8) * 64],
                      &A[(size_t)(m0 + w * 16 + c * 8 + lr) * K + k0 + lcs]);
                gll16(&Bs[nb][(w * 16 + c * 8) * 64],
                      &W[(size_t)(n0 + w * 16 + c * 8 + lr) * K + k0 + lcs]);
            }
        }
        __builtin_amdgcn_sched_barrier(0);

        #pragma unroll
        for (int kh = 0; kh < 2; ++kh) {
            short8 a[2], b[2];
            #pragma unroll
            for (int mt = 0; mt < 2; ++mt)
                a[mt] = *(const short8*)&As[cur][(wm + mt * 16 + ln15) * 64 +
                                                (((kh * 4 + quad) ^ s7) << 3)];
            #pragma unroll
            for (int nt = 0; nt < 2; ++nt)
                b[nt] = *(const short8*)&Bs[cur][(wn + nt * 16 + ln15) * 64 +
                                                (((kh * 4 + quad) ^ s7) << 3)];
            #pragma unroll
            for (int mt = 0; mt < 2; ++mt)
                #pragma unroll
                for (int nt = 0; nt < 2; ++nt)
                    acc[mt][nt] = mfma16(a[mt], b[nt], acc[mt][nt]);
        }
        // no end-of-step barrier: next iteration's barrier provides it
    }

    #pragma unroll
    for (int mt = 0; mt < 2; ++mt)
        #pragma unroll
        for (int nt = 0; nt < 2; ++nt)
            #pragma unroll
            for (int r = 0; r < 4; ++r) {
                int m = m0 + wm + mt * 16 + quad * 4 + r;
                int n = n0 + wn + nt * 16 + ln15;
                out[(size_t)m * 1024 + n] = acc[mt][nt][r] + bias[n];
            }
}

// ---------------------------------------------------------------------------
// Flash attention, causal. Constant-max softmax in exp2 domain (Q carries
// 0.125*log2e; M0L = 6*log2e). P packed to bf16 by v_perm truncation.
// 1024 blocks, bh = id&31; balanced qt map (R11, neutral but harmless).
// DBUF K/V, single barrier per kt, post-barrier staging. Pl stride 64 ->
// LDS 40960 -> 4 blocks/CU. setprio(1) around MFMA clusters (T5: attn
// blocks co-reside at different phases -> scheduler has work to arbitrate).
// V is key-permuted (kl -> (kl&15)*4 + (kl>>4)) to match P's packed layout.
// ---------------------------------------------------------------------------
__global__ __launch_bounds__(256)
void attn3(const u16* __restrict__ Qg, const u16* __restrict__ Kg,
           const u16* __restrict__ Vt, u16* __restrict__ Xb) {
    __shared__ u16 Kl[2][64 * 64];     // [key][d], swizzled, 8 KB each
    __shared__ u16 Vl[2][64 * 64];     // [d][key'], swizzled, 8 KB each
    __shared__ u16 Pl[4][16 * 64];     // per-wave P [q][key'], stride 64

    const int id = blockIdx.x;
    const int bh = id & 31;
    const int kk = id >> 5, jj = kk >> 3, mm = kk & 7;
    const int qt = (jj == 0) ? 31 - mm : (jj == 1) ? mm
                 : (jj == 2) ? 23 - mm : 8 + mm;   // balanced quartets
    const int b = bh >> 4, h = bh & 15;
    const int tid = threadIdx.x, lane = tid & 63, w = tid >> 6;
    const int ln15 = lane & 15, quad = lane >> 4, s7 = ln15 & 7;
    const int lr = lane >> 3;
    const int lcs = (((lane & 7) ^ lr) << 3);
    const u16* Kbase = Kg + (size_t)b * 2048 * 1024 + h * 64;
    const u16* Vbase = Vt + (size_t)bh * 64 * 2048;
    const float M0L = 8.65617025f;     // 6 * log2(e)
    const int q0 = qt * 64;

    const u16* qrow = Qg + (size_t)(b * 2048 + q0 + w * 16 + ln15) * 1024 + h * 64;
    short8 aq0 = *(const short8*)(qrow + quad * 8);
    short8 aq1 = *(const short8*)(qrow + 32 + quad * 8);
    __asm__ volatile("s_waitcnt vmcnt(0)" ::: "memory");   // drain Q loads

    f32x4 o[4] = {};
    float lsum[4] = {0.f, 0.f, 0.f, 0.f};

    #pragma unroll
    for (int c = 0; c < 2; ++c) {
        const int r0 = w * 16 + c * 8;
        gll16(&Kl[0][r0 * 64], Kbase + (size_t)(r0 + lr) * 1024 + lcs);
        gll16(&Vl[0][r0 * 64], Vbase + (size_t)(r0 + lr) * 2048 + lcs);
    }

    for (int kt = 0; kt <= qt; ++kt) {
        const int cur = kt & 1, nb = cur ^ 1;
        __asm__ volatile("s_waitcnt vmcnt(0)" ::: "memory");  // stage(kt) landed
        __builtin_amdgcn_s_barrier();                          // all waves landed
        __builtin_amdgcn_sched_barrier(0);

        if (kt < qt) {                     // stage kt+1 (post-barrier: safe)
            const int nk = (kt + 1) * 64;
            #pragma unroll
            for (int c = 0; c < 2; ++c) {
                const int r0 = w * 16 + c * 8;
                gll16(&Kl[nb][r0 * 64], Kbase + (size_t)(nk + r0 + lr) * 1024 + lcs);
                gll16(&Vl[nb][r0 * 64], Vbase + (size_t)(r0 + lr) * 2048 + nk + lcs);
            }
        }
        __builtin_amdgcn_sched_barrier(0);

        // S = Q(16x64) . K^T(64x64)
        f32x4 sc[4];
        __builtin_amdgcn_s_setprio(1);
        #pragma unroll
        for (int ct = 0; ct < 4; ++ct) {
            short8 b0 = *(const short8*)&Kl[cur][(ct * 16 + ln15) * 64 +
                                                ((quad ^ s7) << 3)];
            short8 b1 = *(const short8*)&Kl[cur][(ct * 16 + ln15) * 64 +
                                                (((4 + quad) ^ s7) << 3)];
            f32x4 c = {};
            c = mfma16(aq0, b0, c);
            c = mfma16(aq1, b1, c);
            sc[ct] = c;
        }
        __builtin_amdgcn_s_setprio(0);

        const bool diag = (kt == qt);
        #pragma unroll
        for (int r = 0; r < 4; ++r) {
            float s0 = sc[0][r], s1 = sc[1][r], s2 = sc[2][r], s3 = sc[3][r];
            if (diag) {
                const int qq = w * 16 + quad * 4 + r;
                s0 = (ln15      <= qq) ? s0 : -1e30f;
                s1 = (16 + ln15 <= qq) ? s1 : -1e30f;
                s2 = (32 + ln15 <= qq) ? s2 : -1e30f;
                s3 = (48 + ln15 <= qq) ? s3 : -1e30f;
            }
            float p0 = __builtin_amdgcn_exp2f(s0 - M0L);
            float p1 = __builtin_amdgcn_exp2f(s1 - M0L);
            float p2 = __builtin_amdgcn_exp2f(s2 - M0L);
            float p3 = __builtin_amdgcn_exp2f(s3 - M0L);
            uint2 pw = make_uint2(pkbf(p1, p0), pkbf(p3, p2));
            *(uint2*)&Pl[w][(quad * 4 + r) * 64 + ln15 * 4] = pw;
            lsum[r] += (p0 + p1) + (p2 + p3);
        }

        __asm__ volatile("s_waitcnt lgkmcnt(0)" ::: "memory");
        short8 ap0 = *(const short8*)&Pl[w][ln15 * 64 + quad * 8];
        short8 ap1 = *(const short8*)&Pl[w][ln15 * 64 + 32 + quad * 8];

        __builtin_amdgcn_s_setprio(1);
        #pragma unroll
        for (int dt = 0; dt < 4; ++dt) {
            short8 bv0 = *(const short8*)&Vl[cur][(dt * 16 + ln15) * 64 +
                                                 ((quad ^ s7) << 3)];
            short8 bv1 = *(const short8*)&Vl[cur][(dt * 16 + ln15) * 64 +
                                                 (((4 + quad) ^ s7) << 3)];
            o[dt] = mfma16(ap0, bv0, o[dt]);
            o[dt] = mfma16(ap1, bv1, o[dt]);
        }
        __builtin_amdgcn_s_setprio(0);
        // no end barrier: next iteration's barrier provides the separation
    }

    #pragma unroll
    for (int r = 0; r < 4; ++r) {
        float l = lsum[r];
        #pragma unroll
        for (int off = 1; off < 16; off <<= 1)
            l += __shfl_xor(l, off);
        lsum[r] = l;
    }
    #pragma unroll
    for (int dt = 0; dt < 4; ++dt)
        #pragma unroll
        for (int r = 0; r < 4; ++r) {
            int q = q0 + w * 16 + quad * 4 + r;
            Xb[(size_t)(b * 2048 + q) * 1024 + h * 64 + dt * 16 + ln15] =
                f2bf(o[dt][r] / lsum[r]);
        }
}

// ---------------------------------------------------------------------------
extern "C" void kernel_launch(void* const* d_in, const int* in_sizes, int n_in,
                              void* d_out, int out_size, void* d_ws, size_t ws_size,
                              hipStream_t stream) {
    const float* query = (const float*)d_in[0];
    const float* key   = (const float*)d_in[1];
    const float* value = (const float*)d_in[2];
    const float* Wq = (const float*)d_in[4];
    const float* Wk = (const float*)d_in[5];
    const float* Wv = (const float*)d_in[6];
    const float* Wo = (const float*)d_in[7];
    const float* bo = (const float*)d_in[8];
    float* out = (float*)d_out;

    u16* ws  = (u16*)d_ws;
    const size_t T = 1ull << 22;          // 4M u16 = 8 MB
    u16* q16 = ws;
    u16* k16 = ws + T;
    u16* v16 = ws + 2 * T;
    u16* w16 = ws + 3 * T;                // 4 x 1M elems
    u16* Qg  = ws + 4 * T;
    u16* Kg  = ws + 5 * T;
    u16* Vt  = (u16*)d_out;               // dead before gemm_out overwrites out
    u16* Xb  = q16;                       // q16 dead after gemm_qkv
    const size_t WSZ = 1ull << 20;

    cvt_all<<<8192, 256, 0, stream>>>(query, key, value, Wq, Wk, Wv, Wo,
                                      q16, k16, v16, w16);

    gemm_qkv<<<dim3(8, 32, 3), 256, 0, stream>>>(q16, k16, v16, w16, Qg, Kg, Vt);

    attn3<<<1024, 256, 0, stream>>>(Qg, Kg, Vt, Xb);

    gemm_out<<<1024, 256, 0, stream>>>(Xb, w16 + 3 * WSZ, bo, out);
}

// Round 13
// 218.583 us; speedup vs baseline: 1.0770x; 1.0061x over previous
//
#include <hip/hip_runtime.h>

// ---------------------------------------------------------------------------
// MHA: B=2, S=2048, HIDDEN=1024, HEADS=16, HEAD=64, causal.
//   0. cvt_all : fp32->bf16; q/k/v and Wq/Wk/Wv written in BLOCK-TILED
//                layout (tile (mb,t) = 128x32 contiguous 16KB) so gemm_qkv
//                staging is fully sequential; Wo stays row-major.
//   1. gemm_qkv: 128x128 tile, BK=32, RING-3 (48KB, 3 blk/CU), distance-2,
//                vmcnt(4); gll16 sources now 1KB-contiguous (tiled A/W).
//   2. attn3   : flash attention, DBUF K/V, Pl stride 64 (4 blk/CU),
//                balanced qt map, setprio around MFMA.
//   3. gemm_out: 64x64 tile, BK=64, 1024 blocks -> 4 blk/CU, dbuf 32KB.
// Tiled layout: panel elem (m,k) -> (m>>7)*131072 + (k>>5)*4096 +
// (m&127)*32 + (k&31). Pure permutation; numerics identical.
// Theory (R12 counters): step = 3780cy vs ~1200cy service estimate; the
// gap is REQUEST COUNT — row-major staging = 16 scattered 64B lines per
// gll16 (rows 2KB apart). Tiled layout -> each gll16 = 1KB contiguous;
// block step staging = one 16KB span. Scatter paid once in cvt (writes),
// not 8-32x on the reuse side (R10 lesson applied in reverse).
// Session ledger (all measured on MI355X):
//  - R3 single-barrier +2.5; R5 BK=32 4blk/CU +6 (occupancy=THE lever);
//    R7 qkv ring-3 +2 / attn ring-3 REGRESSED; R8 64x256 FETCH halved but
//    FLAT (not traffic-bound; plateau ~13 B/cy/CU); R9 attn Pl-64 221.5;
//    R10 fp32-A fold FAILED (materialize conversions once); R11 qt map
//    NEUTRAL; R12 gemm_out 64x64 + attn setprio 219.9 (BEST).
//  - This round: tiled staging layout for gemm_qkv A/B panels.
// ---------------------------------------------------------------------------

typedef __attribute__((ext_vector_type(8))) short short8;   // 8 bf16
typedef __attribute__((ext_vector_type(4))) float f32x4;
typedef unsigned int u32;
typedef unsigned short u16;

__device__ inline f32x4 mfma16(short8 a, short8 b, f32x4 c) {
    return __builtin_amdgcn_mfma_f32_16x16x32_bf16(a, b, c, 0, 0, 0);
}
__device__ inline u16 f2bf(float f) {
    union { float f; u32 u; } v; v.f = f;
    u32 r = v.u + 0x7fff + ((v.u >> 16) & 1);   // RNE
    return (u16)(r >> 16);
}
__device__ inline void gll16(void* lds, const void* g) {
    __builtin_amdgcn_global_load_lds((const __attribute__((address_space(1))) u32*)g,
                                     (__attribute__((address_space(3))) u32*)lds,
                                     16, 0, 0);
}
// pack two fp32 -> two bf16 (truncation) in one v_perm: mem order lo,hi
__device__ inline u32 pkbf(float hi, float lo) {
    return __builtin_amdgcn_perm(__float_as_uint(hi), __float_as_uint(lo),
                                 0x07060302u);
}

// ---------------------------------------------------------------------------
// cvt_all: q/k/v and Wq/Wk/Wv written TILED for gemm_qkv staging;
// Wo (wi==3) stays row-major for gemm_out.
// ---------------------------------------------------------------------------
__global__ __launch_bounds__(256)
void cvt_all(const float* __restrict__ q, const float* __restrict__ k,
             const float* __restrict__ v, const float* __restrict__ wq,
             const float* __restrict__ wk, const float* __restrict__ wv,
             const float* __restrict__ wo,
             u16* __restrict__ q16, u16* __restrict__ k16,
             u16* __restrict__ v16, u16* __restrict__ w16) {
    const size_t QKV = 1u << 22;
    const size_t WSZ = 1u << 20;
    size_t base = ((size_t)blockIdx.x * 256 + threadIdx.x) * 8;
    const float* src; u16* dst; size_t off; float scale = 1.0f;
    bool tiled = true;
    if (base < QKV)            { src = q; dst = q16; off = base;
                                 scale = 0.125f * 1.44269504f; }   // exp2 domain
    else if (base < 2 * QKV)   { src = k; dst = k16; off = base - QKV;     }
    else if (base < 3 * QKV)   { src = v; dst = v16; off = base - 2 * QKV; }
    else {
        size_t wb = base - 3 * QKV;
        int wi = (int)(wb >> 20); off = wb & (WSZ - 1);
        src = wi == 0 ? wq : wi == 1 ? wk : wi == 2 ? wv : wo;
        dst = w16 + (size_t)wi * WSZ;
        tiled = (wi != 3);             // Wo stays row-major for gemm_out
    }
    float4 f0 = *(const float4*)(src + off);
    float4 f1 = *(const float4*)(src + off + 4);
    short8 s = { (short)f2bf(f0.x * scale), (short)f2bf(f0.y * scale),
                 (short)f2bf(f0.z * scale), (short)f2bf(f0.w * scale),
                 (short)f2bf(f1.x * scale), (short)f2bf(f1.y * scale),
                 (short)f2bf(f1.z * scale), (short)f2bf(f1.w * scale) };
    size_t didx = off;
    if (tiled) {
        size_t m = off >> 10, kk = off & 1023;   // row, col in panel (K=1024)
        didx = ((m >> 7) * 131072) + ((kk >> 5) * 4096)
             + ((m & 127) * 32) + (kk & 31);     // 8 consecutive k -> contiguous
    }
    *(short8*)(dst + didx) = s;
}

// ---------------------------------------------------------------------------
// Fused QKV GEMM. C[m,n] = sum_k A[m,k]*W[n,k]. grid (8,32,3), 256 thr.
// 128x128 tile, BK=32, ring-3 LDS (48KB), distance-2 prefetch, vmcnt(4).
// A/W panels are TILED: tile t of panel mb at mb*131072 + t*4096,
// 128 rows x 32 cols contiguous. Each gll16 reads 1KB sequential.
// ---------------------------------------------------------------------------
__global__ __launch_bounds__(256)
void gemm_qkv(const u16* __restrict__ q16, const u16* __restrict__ k16,
              const u16* __restrict__ v16, const u16* __restrict__ w16,
              u16* __restrict__ Qg, u16* __restrict__ Kg, u16* __restrict__ Vt) {
    __shared__ u16 As[3][128 * 32];    // 8 KB per buffer
    __shared__ u16 Bs[3][128 * 32];    // total 48 KB
    const int z = blockIdx.z;
    const u16* A = z == 0 ? q16 : z == 1 ? k16 : v16;
    const u16* W = w16 + (size_t)z * (1u << 20);

    const int tid = threadIdx.x, lane = tid & 63, w = tid >> 6;
    const int ln15 = lane & 15, quad = lane >> 4;
    const int fr = (ln15 >> 1) & 3;              // read-side granule swizzle
    const int lrow = lane >> 2;                  // 16 rows per gll16
    const int lcs = (((lane & 3) ^ ((lane >> 3) & 3)) << 3);  // src granule perm
    const int m0 = blockIdx.y * 128, n0 = blockIdx.x * 128;
    const size_t mbase = (size_t)blockIdx.y * 131072;   // tiled panel base
    const size_t nbase = (size_t)blockIdx.x * 131072;
    const int wm = (w >> 1) * 64, wn = (w & 1) * 64;

    f32x4 acc[4][4] = {};

    // prologue: stage K-tiles 0 and 1 (4 loads each per wave -> 8 in flight)
    #pragma unroll
    for (int t = 0; t < 2; ++t)
        #pragma unroll
        for (int c = 0; c < 2; ++c) {
            const int r0 = w * 32 + c * 16;
            gll16(&As[t][r0 * 32],
                  &A[mbase + (size_t)t * 4096 + (r0 + lrow) * 32 + lcs]);
            gll16(&Bs[t][r0 * 32],
                  &W[nbase + (size_t)t * 4096 + (r0 + lrow) * 32 + lcs]);
        }

    int cur = 0;                       // t % 3
    for (int t = 0; t < 32; ++t) {
        if (t < 31) {
            __asm__ volatile("s_waitcnt vmcnt(4)" ::: "memory");  // stage(t) landed
        } else {
            __asm__ volatile("s_waitcnt vmcnt(0)" ::: "memory");
        }
        __builtin_amdgcn_s_barrier();                              // all waves landed
        __builtin_amdgcn_sched_barrier(0);

        if (t < 30) {                  // stage tile t+2 (post-barrier: safe)
            const size_t kb = (size_t)(t + 2) * 4096;
            const int nb = (cur + 2 >= 3) ? cur - 1 : cur + 2;     // (t+2)%3
            #pragma unroll
            for (int c = 0; c < 2; ++c) {
                const int r0 = w * 32 + c * 16;
                gll16(&As[nb][r0 * 32],
                      &A[mbase + kb + (r0 + lrow) * 32 + lcs]);
                gll16(&Bs[nb][r0 * 32],
                      &W[nbase + kb + (r0 + lrow) * 32 + lcs]);
            }
        }
        __builtin_amdgcn_sched_barrier(0);  // pin stage issue before compute

        short8 a[4], b[4];
        #pragma unroll
        for (int mt = 0; mt < 4; ++mt)
            a[mt] = *(const short8*)&As[cur][(wm + mt * 16 + ln15) * 32 +
                                            ((quad ^ fr) << 3)];
        #pragma unroll
        for (int nt = 0; nt < 4; ++nt)
            b[nt] = *(const short8*)&Bs[cur][(wn + nt * 16 + ln15) * 32 +
                                            ((quad ^ fr) << 3)];
        #pragma unroll
        for (int mt = 0; mt < 4; ++mt)
            #pragma unroll
            for (int nt = 0; nt < 4; ++nt)
                acc[mt][nt] = mfma16(a[mt], b[nt], acc[mt][nt]);

        cur = (cur == 2) ? 0 : cur + 1;
        // no end-of-step barrier: next iteration's barrier provides it
    }

    #pragma unroll
    for (int mt = 0; mt < 4; ++mt)
        #pragma unroll
        for (int nt = 0; nt < 4; ++nt)
            #pragma unroll
            for (int r = 0; r < 4; ++r) {
                int m = m0 + wm + mt * 16 + quad * 4 + r;
                int n = n0 + wn + nt * 16 + ln15;
                u16 hv = f2bf(acc[mt][nt][r]);
                if (z == 2) {
                    int b_ = m >> 11, s_ = m & 2047, h_ = n >> 6, d_ = n & 63;
                    int kl = s_ & 63;
                    int sp = (s_ & ~63) + (kl & 15) * 4 + (kl >> 4);  // key perm
                    Vt[((size_t)(b_ * 16 + h_) * 64 + d_) * 2048 + sp] = hv;
                } else {
                    u16* dst = z ? Kg : Qg;
                    dst[(size_t)m * 1024 + n] = hv;
                }
            }
}

// ---------------------------------------------------------------------------
// Output GEMM: 64x64 tile, BK=64, 1024 blocks -> 4 blocks/CU, ONE round.
// dbuf 32KB, single barrier/step, post-barrier staging (R12 config).
// ---------------------------------------------------------------------------
__global__ __launch_bounds__(256)
void gemm_out(const u16* __restrict__ A, const u16* __restrict__ W,
              const float* __restrict__ bias, float* __restrict__ out) {
    const int K = 1024;
    __shared__ u16 As[2][64 * 64];     // 8 KB per buffer
    __shared__ u16 Bs[2][64 * 64];     // 8 KB per buffer -> 32 KB total
    const int id = blockIdx.x;
    const int by = id >> 4, bx = id & 15;  // 16 sharers of A-panel spread XCDs

    const int tid = threadIdx.x, lane = tid & 63, w = tid >> 6;
    const int ln15 = lane & 15, quad = lane >> 4, s7 = ln15 & 7;
    const int lr = lane >> 3;
    const int lcs = (((lane & 7) ^ lr) << 3);
    const int m0 = by * 64, n0 = bx * 64;
    const int wm = (w & 1) * 32, wn = (w >> 1) * 32;

    f32x4 acc[2][2] = {};

    #pragma unroll
    for (int c = 0; c < 2; ++c) {
        gll16(&As[0][(w * 16 + c * 8) * 64],
              &A[(size_t)(m0 + w * 16 + c * 8 + lr) * K + lcs]);
        gll16(&Bs[0][(w * 16 + c * 8) * 64],
              &W[(size_t)(n0 + w * 16 + c * 8 + lr) * K + lcs]);
    }

    for (int i = 0; i < 16; ++i) {
        const int cur = i & 1, nb = cur ^ 1;
        __asm__ volatile("s_waitcnt vmcnt(0)" ::: "memory");  // own stage landed
        __builtin_amdgcn_s_barrier();                          // all waves landed
        __builtin_amdgcn_sched_barrier(0);

        if (i < 15) {                       // stage tile i+1 (post-barrier: safe)
            const int k0 = (i + 1) * 64;
            #pragma unroll
            for (int c = 0; c < 2; ++c) {
                gll16(&As[nb][(w * 16 + c * 8) * 64],
                      &A[(size_t)(m0 + w * 16 + c * 8 + lr) * K + k0 + lcs]);
                gll16(&Bs[nb][(w * 16 + c * 8) * 64],
                      &W[(size_t)(n0 + w * 16 + c * 8 + lr) * K + k0 + lcs]);
            }
        }
        __builtin_amdgcn_sched_barrier(0);

        #pragma unroll
        for (int kh = 0; kh < 2; ++kh) {
            short8 a[2], b[2];
            #pragma unroll
            for (int mt = 0; mt < 2; ++mt)
                a[mt] = *(const short8*)&As[cur][(wm + mt * 16 + ln15) * 64 +
                                                (((kh * 4 + quad) ^ s7) << 3)];
            #pragma unroll
            for (int nt = 0; nt < 2; ++nt)
                b[nt] = *(const short8*)&Bs[cur][(wn + nt * 16 + ln15) * 64 +
                                                (((kh * 4 + quad) ^ s7) << 3)];
            #pragma unroll
            for (int mt = 0; mt < 2; ++mt)
                #pragma unroll
                for (int nt = 0; nt < 2; ++nt)
                    acc[mt][nt] = mfma16(a[mt], b[nt], acc[mt][nt]);
        }
        // no end-of-step barrier: next iteration's barrier provides it
    }

    #pragma unroll
    for (int mt = 0; mt < 2; ++mt)
        #pragma unroll
        for (int nt = 0; nt < 2; ++nt)
            #pragma unroll
            for (int r = 0; r < 4; ++r) {
                int m = m0 + wm + mt * 16 + quad * 4 + r;
                int n = n0 + wn + nt * 16 + ln15;
                out[(size_t)m * 1024 + n] = acc[mt][nt][r] + bias[n];
            }
}

// ---------------------------------------------------------------------------
// Flash attention, causal. Constant-max softmax in exp2 domain (Q carries
// 0.125*log2e; M0L = 6*log2e). P packed to bf16 by v_perm truncation.
// 1024 blocks, bh = id&31; balanced qt map. DBUF K/V, single barrier/kt,
// post-barrier staging. Pl stride 64 -> LDS 40960 -> 4 blocks/CU.
// setprio(1) around MFMA clusters. V key-permuted (kl->(kl&15)*4+(kl>>4)).
// ---------------------------------------------------------------------------
__global__ __launch_bounds__(256)
void attn3(const u16* __restrict__ Qg, const u16* __restrict__ Kg,
           const u16* __restrict__ Vt, u16* __restrict__ Xb) {
    __shared__ u16 Kl[2][64 * 64];     // [key][d], swizzled, 8 KB each
    __shared__ u16 Vl[2][64 * 64];     // [d][key'], swizzled, 8 KB each
    __shared__ u16 Pl[4][16 * 64];     // per-wave P [q][key'], stride 64

    const int id = blockIdx.x;
    const int bh = id & 31;
    const int kk = id >> 5, jj = kk >> 3, mm = kk & 7;
    const int qt = (jj == 0) ? 31 - mm : (jj == 1) ? mm
                 : (jj == 2) ? 23 - mm : 8 + mm;   // balanced quartets
    const int b = bh >> 4, h = bh & 15;
    const int tid = threadIdx.x, lane = tid & 63, w = tid >> 6;
    const int ln15 = lane & 15, quad = lane >> 4, s7 = ln15 & 7;
    const int lr = lane >> 3;
    const int lcs = (((lane & 7) ^ lr) << 3);
    const u16* Kbase = Kg + (size_t)b * 2048 * 1024 + h * 64;
    const u16* Vbase = Vt + (size_t)bh * 64 * 2048;
    const float M0L = 8.65617025f;     // 6 * log2(e)
    const int q0 = qt * 64;

    const u16* qrow = Qg + (size_t)(b * 2048 + q0 + w * 16 + ln15) * 1024 + h * 64;
    short8 aq0 = *(const short8*)(qrow + quad * 8);
    short8 aq1 = *(const short8*)(qrow + 32 + quad * 8);
    __asm__ volatile("s_waitcnt vmcnt(0)" ::: "memory");   // drain Q loads

    f32x4 o[4] = {};
    float lsum[4] = {0.f, 0.f, 0.f, 0.f};

    #pragma unroll
    for (int c = 0; c < 2; ++c) {
        const int r0 = w * 16 + c * 8;
        gll16(&Kl[0][r0 * 64], Kbase + (size_t)(r0 + lr) * 1024 + lcs);
        gll16(&Vl[0][r0 * 64], Vbase + (size_t)(r0 + lr) * 2048 + lcs);
    }

    for (int kt = 0; kt <= qt; ++kt) {
        const int cur = kt & 1, nb = cur ^ 1;
        __asm__ volatile("s_waitcnt vmcnt(0)" ::: "memory");  // stage(kt) landed
        __builtin_amdgcn_s_barrier();                          // all waves landed
        __builtin_amdgcn_sched_barrier(0);

        if (kt < qt) {                     // stage kt+1 (post-barrier: safe)
            const int nk = (kt + 1) * 64;
            #pragma unroll
            for (int c = 0; c < 2; ++c) {
                const int r0 = w * 16 + c * 8;
                gll16(&Kl[nb][r0 * 64], Kbase + (size_t)(nk + r0 + lr) * 1024 + lcs);
                gll16(&Vl[nb][r0 * 64], Vbase + (size_t)(r0 + lr) * 2048 + nk + lcs);
            }
        }
        __builtin_amdgcn_sched_barrier(0);

        // S = Q(16x64) . K^T(64x64)
        f32x4 sc[4];
        __builtin_amdgcn_s_setprio(1);
        #pragma unroll
        for (int ct = 0; ct < 4; ++ct) {
            short8 b0 = *(const short8*)&Kl[cur][(ct * 16 + ln15) * 64 +
                                                ((quad ^ s7) << 3)];
            short8 b1 = *(const short8*)&Kl[cur][(ct * 16 + ln15) * 64 +
                                                (((4 + quad) ^ s7) << 3)];
            f32x4 c = {};
            c = mfma16(aq0, b0, c);
            c = mfma16(aq1, b1, c);
            sc[ct] = c;
        }
        __builtin_amdgcn_s_setprio(0);

        const bool diag = (kt == qt);
        #pragma unroll
        for (int r = 0; r < 4; ++r) {
            float s0 = sc[0][r], s1 = sc[1][r], s2 = sc[2][r], s3 = sc[3][r];
            if (diag) {
                const int qq = w * 16 + quad * 4 + r;
                s0 = (ln15      <= qq) ? s0 : -1e30f;
                s1 = (16 + ln15 <= qq) ? s1 : -1e30f;
                s2 = (32 + ln15 <= qq) ? s2 : -1e30f;
                s3 = (48 + ln15 <= qq) ? s3 : -1e30f;
            }
            float p0 = __builtin_amdgcn_exp2f(s0 - M0L);
            float p1 = __builtin_amdgcn_exp2f(s1 - M0L);
            float p2 = __builtin_amdgcn_exp2f(s2 - M0L);
            float p3 = __builtin_amdgcn_exp2f(s3 - M0L);
            uint2 pw = make_uint2(pkbf(p1, p0), pkbf(p3, p2));
            *(uint2*)&Pl[w][(quad * 4 + r) * 64 + ln15 * 4] = pw;
            lsum[r] += (p0 + p1) + (p2 + p3);
        }

        __asm__ volatile("s_waitcnt lgkmcnt(0)" ::: "memory");
        short8 ap0 = *(const short8*)&Pl[w][ln15 * 64 + quad * 8];
        short8 ap1 = *(const short8*)&Pl[w][ln15 * 64 + 32 + quad * 8];

        __builtin_amdgcn_s_setprio(1);
        #pragma unroll
        for (int dt = 0; dt < 4; ++dt) {
            short8 bv0 = *(const short8*)&Vl[cur][(dt * 16 + ln15) * 64 +
                                                 ((quad ^ s7) << 3)];
            short8 bv1 = *(const short8*)&Vl[cur][(dt * 16 + ln15) * 64 +
                                                 (((4 + quad) ^ s7) << 3)];
            o[dt] = mfma16(ap0, bv0, o[dt]);
            o[dt] = mfma16(ap1, bv1, o[dt]);
        }
        __builtin_amdgcn_s_setprio(0);
        // no end barrier: next iteration's barrier provides the separation
    }

    #pragma unroll
    for (int r = 0; r < 4; ++r) {
        float l = lsum[r];
        #pragma unroll
        for (int off = 1; off < 16; off <<= 1)
            l += __shfl_xor(l, off);
        lsum[r] = l;
    }
    #pragma unroll
    for (int dt = 0; dt < 4; ++dt)
        #pragma unroll
        for (int r = 0; r < 4; ++r) {
            int q = q0 + w * 16 + quad * 4 + r;
            Xb[(size_t)(b * 2048 + q) * 1024 + h * 64 + dt * 16 + ln15] =
                f2bf(o[dt][r] / lsum[r]);
        }
}

// ---------------------------------------------------------------------------
extern "C" void kernel_launch(void* const* d_in, const int* in_sizes, int n_in,
                              void* d_out, int out_size, void* d_ws, size_t ws_size,
                              hipStream_t stream) {
    const float* query = (const float*)d_in[0];
    const float* key   = (const float*)d_in[1];
    const float* value = (const float*)d_in[2];
    const float* Wq = (const float*)d_in[4];
    const float* Wk = (const float*)d_in[5];
    const float* Wv = (const float*)d_in[6];
    const float* Wo = (const float*)d_in[7];
    const float* bo = (const float*)d_in[8];
    float* out = (float*)d_out;

    u16* ws  = (u16*)d_ws;
    const size_t T = 1ull << 22;          // 4M u16 = 8 MB
    u16* q16 = ws;
    u16* k16 = ws + T;
    u16* v16 = ws + 2 * T;
    u16* w16 = ws + 3 * T;                // 4 x 1M elems
    u16* Qg  = ws + 4 * T;
    u16* Kg  = ws + 5 * T;
    u16* Vt  = (u16*)d_out;               // dead before gemm_out overwrites out
    u16* Xb  = q16;                       // q16 dead after gemm_qkv
    const size_t WSZ = 1ull << 20;

    cvt_all<<<8192, 256, 0, stream>>>(query, key, value, Wq, Wk, Wv, Wo,
                                      q16, k16, v16, w16);

    gemm_qkv<<<dim3(8, 32, 3), 256, 0, stream>>>(q16, k16, v16, w16, Qg, Kg, Vt);

    attn3<<<1024, 256, 0, stream>>>(Qg, Kg, Vt, Xb);

    gemm_out<<<1024, 256, 0, stream>>>(Xb, w16 + 3 * WSZ, bo, out);
}